// Round 1
// baseline (884.503 us; speedup 1.0000x reference)
//
#include <hip/hip_runtime.h>
#include <hip/hip_bf16.h>
#include <math.h>

#define L_SEQ 2048
#define DMODEL 512
#define NH 8
#define HD 64

// log2(10000)/32
#define ROPE_C 0.4152410118609203f

// ---------------------------------------------------------------------------
// Kernel 1: QKV projection (y = x @ W.T + b), head split, RoPE for Q/K.
// Tiled 64x64 GEMM, 256 threads, 4x4 micro-tile, K-chunk 32.
// grid: (4096/64, 512/64, 3)   z: 0=Q 1=K 2=V
// ---------------------------------------------------------------------------
__global__ __launch_bounds__(256) void qkv_proj_rope(
    const float* __restrict__ x,
    const float* __restrict__ Wq, const float* __restrict__ bq,
    const float* __restrict__ Wk, const float* __restrict__ bk,
    const float* __restrict__ Wv, const float* __restrict__ bv,
    float* __restrict__ Qws, float* __restrict__ Kws, float* __restrict__ Vws)
{
    const int z = blockIdx.z;
    const float* __restrict__ W    = (z == 0) ? Wq : (z == 1) ? Wk : Wv;
    const float* __restrict__ bias = (z == 0) ? bq : (z == 1) ? bk : bv;
    float* __restrict__ outp       = (z == 0) ? Qws : (z == 1) ? Kws : Vws;

    __shared__ float Xs[64][33];
    __shared__ float Wt[64][33];

    const int t  = threadIdx.x;
    const int tx = t & 15, ty = t >> 4;
    const int mbase = blockIdx.x * 64;
    const int nbase = blockIdx.y * 64;

    const int lrow = t >> 3;        // 0..31
    const int lk4  = (t & 7) << 2;  // 0..28

    float acc[4][4] = {};

    for (int k0 = 0; k0 < DMODEL; k0 += 32) {
        __syncthreads();
        #pragma unroll
        for (int rr = 0; rr < 64; rr += 32) {
            float4 xv = *(const float4*)(&x[(size_t)(mbase + lrow + rr) * DMODEL + k0 + lk4]);
            Xs[lrow + rr][lk4 + 0] = xv.x;
            Xs[lrow + rr][lk4 + 1] = xv.y;
            Xs[lrow + rr][lk4 + 2] = xv.z;
            Xs[lrow + rr][lk4 + 3] = xv.w;
            float4 wv = *(const float4*)(&W[(size_t)(nbase + lrow + rr) * DMODEL + k0 + lk4]);
            Wt[lrow + rr][lk4 + 0] = wv.x;
            Wt[lrow + rr][lk4 + 1] = wv.y;
            Wt[lrow + rr][lk4 + 2] = wv.z;
            Wt[lrow + rr][lk4 + 3] = wv.w;
        }
        __syncthreads();
        #pragma unroll 8
        for (int kk = 0; kk < 32; ++kk) {
            float a[4], b[4];
            #pragma unroll
            for (int i = 0; i < 4; ++i) a[i] = Xs[(ty << 2) + i][kk];
            #pragma unroll
            for (int j = 0; j < 4; ++j) b[j] = Wt[(tx << 2) + j][kk];
            #pragma unroll
            for (int i = 0; i < 4; ++i)
                #pragma unroll
                for (int j = 0; j < 4; ++j)
                    acc[i][j] += a[i] * b[j];
        }
    }

    const int jg0  = nbase + (tx << 2);
    const int head = jg0 >> 6;
    const int dim0 = jg0 & 63;
    const float b0 = bias[jg0 + 0], b1 = bias[jg0 + 1],
                b2 = bias[jg0 + 2], b3 = bias[jg0 + 3];

    #pragma unroll
    for (int i = 0; i < 4; ++i) {
        const int ig  = mbase + (ty << 2) + i;
        const int bb  = ig >> 11;     // batch
        const int pos = ig & 2047;
        float v0 = acc[i][0] + b0;
        float v1 = acc[i][1] + b1;
        float v2 = acc[i][2] + b2;
        float v3 = acc[i][3] + b3;
        if (z < 2) {
            const float fpos = (float)pos;
            const int d2a = dim0 >> 1;
            const int d2b = d2a + 1;
            const float invfa = exp2f(-ROPE_C * (float)d2a);
            const float invfb = exp2f(-ROPE_C * (float)d2b);
            float sa, ca, sb, cb;
            sincosf(fpos * invfa, &sa, &ca);
            sincosf(fpos * invfb, &sb, &cb);
            const float r0 = v0 * ca - v1 * sa;
            const float r1 = v1 * ca + v0 * sa;
            const float r2 = v2 * cb - v3 * sb;
            const float r3 = v3 * cb + v2 * sb;
            v0 = r0; v1 = r1; v2 = r2; v3 = r3;
        }
        *(float4*)(&outp[(((size_t)bb * NH + head) * L_SEQ + pos) * HD + dim0]) =
            make_float4(v0, v1, v2, v3);
    }
}

// ---------------------------------------------------------------------------
// Kernel 2: strictly-upper causal tiles: score = -1e9 exactly (|prev| < ulp/2)
// grid: (2048, 16) blocks of 256
// ---------------------------------------------------------------------------
__global__ __launch_bounds__(256) void fill_upper(float* __restrict__ out_score)
{
    const int q  = blockIdx.x;
    const int bh = blockIdx.y;
    const int kstart = ((q >> 6) + 1) << 6;   // first tile strictly above diag
    float4* row = (float4*)(out_score + ((size_t)bh * L_SEQ + q) * L_SEQ);
    const float4 fv = make_float4(-1e9f, -1e9f, -1e9f, -1e9f);
    for (int c4 = (kstart >> 2) + threadIdx.x; c4 < (L_SEQ >> 2); c4 += 256)
        row[c4] = fv;
}

// ---------------------------------------------------------------------------
// Kernel 3: fused causal attention with score write-out + online softmax.
// One block per (bh, q-tile of 64). 256 threads, 4x4 micro-tiles.
// LDS: Qs + (K aliased with P) + Vs, stride 65 (conflict <= 2-way).
// grid: 512 (g = qtr*16 + bh; qt pairing balances causal work)
// ---------------------------------------------------------------------------
__global__ __launch_bounds__(256) void attn_fused(
    const float* __restrict__ Qws, const float* __restrict__ Kws,
    const float* __restrict__ Vws, const float* __restrict__ prev,
    float* __restrict__ out_o, float* __restrict__ out_score)
{
    __shared__ float Qs[64][65];
    __shared__ float KPs[64][65];   // K tile; re-used as P tile
    __shared__ float Vs[64][65];

    const int g   = blockIdx.x;
    const int bh  = g & 15;
    const int qtr = g >> 4;                       // 0..31
    const int qt  = (qtr < 16) ? qtr : 47 - qtr;  // complementary pairing
    const int t   = threadIdx.x;
    const int tx  = t & 15, ty = t >> 4;
    const int qbase = qt << 6;

    const size_t hoff = (size_t)bh * L_SEQ * HD;
    const int lc4 = (t & 15) << 2;
    const int lr0 = t >> 4;

    // load Q tile
    #pragma unroll
    for (int rr = 0; rr < 4; ++rr) {
        const int row = lr0 + rr * 16;
        float4 qv = *(const float4*)(&Qws[hoff + (size_t)(qbase + row) * HD + lc4]);
        Qs[row][lc4 + 0] = qv.x; Qs[row][lc4 + 1] = qv.y;
        Qs[row][lc4 + 2] = qv.z; Qs[row][lc4 + 3] = qv.w;
    }

    float accO[4][4] = {};
    float m_i[4] = {-INFINITY, -INFINITY, -INFINITY, -INFINITY};
    float l_i[4] = {};

    const size_t prow0 = ((size_t)bh * L_SEQ + qbase) * L_SEQ;

    for (int kt = 0; kt <= qt; ++kt) {
        const int kbase = kt << 6;
        __syncthreads();  // previous PV done with KPs/Vs
        #pragma unroll
        for (int rr = 0; rr < 4; ++rr) {
            const int row = lr0 + rr * 16;
            float4 kv = *(const float4*)(&Kws[hoff + (size_t)(kbase + row) * HD + lc4]);
            KPs[row][lc4 + 0] = kv.x; KPs[row][lc4 + 1] = kv.y;
            KPs[row][lc4 + 2] = kv.z; KPs[row][lc4 + 3] = kv.w;
            float4 vv = *(const float4*)(&Vws[hoff + (size_t)(kbase + row) * HD + lc4]);
            Vs[row][lc4 + 0] = vv.x; Vs[row][lc4 + 1] = vv.y;
            Vs[row][lc4 + 2] = vv.z; Vs[row][lc4 + 3] = vv.w;
        }
        __syncthreads();

        // S = Q K^T
        float s[4][4] = {};
        #pragma unroll 16
        for (int kk = 0; kk < 64; ++kk) {
            float a[4], b[4];
            #pragma unroll
            for (int i = 0; i < 4; ++i) a[i] = Qs[(ty << 2) + i][kk];
            #pragma unroll
            for (int j = 0; j < 4; ++j) b[j] = KPs[(tx << 2) + j][kk];
            #pragma unroll
            for (int i = 0; i < 4; ++i)
                #pragma unroll
                for (int j = 0; j < 4; ++j)
                    s[i][j] += a[i] * b[j];
        }

        // scale + mask + prev, write score
        #pragma unroll
        for (int i = 0; i < 4; ++i) {
            const int q = qbase + (ty << 2) + i;
            const size_t off = prow0 + (size_t)((ty << 2) + i) * L_SEQ + kbase + (tx << 2);
            const float4 pv = *(const float4*)(&prev[off]);
            const int kc = kbase + (tx << 2);
            const float v0 = (kc + 0 <= q) ? fmaf(s[i][0], 0.125f, pv.x) : -1e9f;
            const float v1 = (kc + 1 <= q) ? fmaf(s[i][1], 0.125f, pv.y) : -1e9f;
            const float v2 = (kc + 2 <= q) ? fmaf(s[i][2], 0.125f, pv.z) : -1e9f;
            const float v3 = (kc + 3 <= q) ? fmaf(s[i][3], 0.125f, pv.w) : -1e9f;
            s[i][0] = v0; s[i][1] = v1; s[i][2] = v2; s[i][3] = v3;
            *(float4*)(&out_score[off]) = make_float4(v0, v1, v2, v3);
        }

        // online softmax update (16-lane row groups)
        float p[4][4];
        #pragma unroll
        for (int i = 0; i < 4; ++i) {
            float mx = fmaxf(fmaxf(s[i][0], s[i][1]), fmaxf(s[i][2], s[i][3]));
            mx = fmaxf(mx, __shfl_xor(mx, 1));
            mx = fmaxf(mx, __shfl_xor(mx, 2));
            mx = fmaxf(mx, __shfl_xor(mx, 4));
            mx = fmaxf(mx, __shfl_xor(mx, 8));
            const float mnew = fmaxf(m_i[i], mx);
            const float sc = __expf(m_i[i] - mnew);   // first iter: exp(-inf)=0
            float p0 = __expf(s[i][0] - mnew);
            float p1 = __expf(s[i][1] - mnew);
            float p2 = __expf(s[i][2] - mnew);
            float p3 = __expf(s[i][3] - mnew);
            float sum = p0 + p1 + p2 + p3;
            sum += __shfl_xor(sum, 1);
            sum += __shfl_xor(sum, 2);
            sum += __shfl_xor(sum, 4);
            sum += __shfl_xor(sum, 8);
            l_i[i] = l_i[i] * sc + sum;
            m_i[i] = mnew;
            accO[i][0] *= sc; accO[i][1] *= sc; accO[i][2] *= sc; accO[i][3] *= sc;
            p[i][0] = p0; p[i][1] = p1; p[i][2] = p2; p[i][3] = p3;
        }

        __syncthreads();  // everyone done reading K from KPs
        #pragma unroll
        for (int i = 0; i < 4; ++i)
            #pragma unroll
            for (int j = 0; j < 4; ++j)
                KPs[(ty << 2) + i][(tx << 2) + j] = p[i][j];
        __syncthreads();  // P visible

        // O += P V
        #pragma unroll 16
        for (int kk = 0; kk < 64; ++kk) {
            float a[4], b[4];
            #pragma unroll
            for (int i = 0; i < 4; ++i) a[i] = KPs[(ty << 2) + i][kk];
            #pragma unroll
            for (int j = 0; j < 4; ++j) b[j] = Vs[kk][(tx << 2) + j];
            #pragma unroll
            for (int i = 0; i < 4; ++i)
                #pragma unroll
                for (int j = 0; j < 4; ++j)
                    accO[i][j] += a[i] * b[j];
        }
    }

    // epilogue: O /= l, write (b, L, h*64+hd)
    const int bb = bh >> 3, hh = bh & 7;
    #pragma unroll
    for (int i = 0; i < 4; ++i) {
        const int q = qbase + (ty << 2) + i;
        const float inv = 1.0f / l_i[i];
        *(float4*)(&out_o[((size_t)bb * L_SEQ + q) * DMODEL + hh * HD + (tx << 2)]) =
            make_float4(accO[i][0] * inv, accO[i][1] * inv,
                        accO[i][2] * inv, accO[i][3] * inv);
    }
}

// ---------------------------------------------------------------------------
extern "C" void kernel_launch(void* const* d_in, const int* in_sizes, int n_in,
                              void* d_out, int out_size, void* d_ws, size_t ws_size,
                              hipStream_t stream)
{
    const float* x    = (const float*)d_in[0];
    const float* prev = (const float*)d_in[1];
    const float* Wq   = (const float*)d_in[2];
    const float* bq   = (const float*)d_in[3];
    const float* Wk   = (const float*)d_in[4];
    const float* bk   = (const float*)d_in[5];
    const float* Wv   = (const float*)d_in[6];
    const float* bv   = (const float*)d_in[7];

    float* out_o     = (float*)d_out;
    float* out_score = out_o + (size_t)2 * L_SEQ * DMODEL;

    const size_t qkv_elems = (size_t)2 * NH * L_SEQ * HD;  // 2,097,152
    float* Qws = (float*)d_ws;
    float* Kws = Qws + qkv_elems;
    float* Vws = Kws + qkv_elems;

    qkv_proj_rope<<<dim3(4096 / 64, DMODEL / 64, 3), 256, 0, stream>>>(
        x, Wq, bq, Wk, bk, Wv, bv, Qws, Kws, Vws);

    fill_upper<<<dim3(L_SEQ, 16), 256, 0, stream>>>(out_score);

    attn_fused<<<dim3(512), 256, 0, stream>>>(Qws, Kws, Vws, prev, out_o, out_score);
}

// Round 2
// 870.174 us; speedup vs baseline: 1.0165x; 1.0165x over previous
//
#include <hip/hip_runtime.h>
#include <hip/hip_bf16.h>
#include <math.h>

#define L_SEQ 2048
#define DMODEL 512
#define NH 8
#define HD 64

// log2(10000)/32
#define ROPE_C 0.4152410118609203f

// ---------------------------------------------------------------------------
// XOR-chunk swizzle for [*][64] float tiles: physical 16B-chunk = c4 ^ ((r>>2)&15).
// Rows stay 256B apart => every float4 slot is 16B aligned; reads along a row
// with per-lane row index r=4*lane+j give 16 distinct chunk windows (conflict-free).
// ---------------------------------------------------------------------------
__device__ __forceinline__ int tix(int r, int c) {
    return r * 64 + ((((c >> 2) ^ ((r >> 2) & 15)) << 2) | (c & 3));
}
__device__ __forceinline__ float4* tix4(float* buf, int r, int c4) {
    return reinterpret_cast<float4*>(buf + r * 64 + ((c4 ^ ((r >> 2) & 15)) << 2));
}
__device__ __forceinline__ const float4* tix4c(const float* buf, int r, int c4) {
    return reinterpret_cast<const float4*>(buf + r * 64 + ((c4 ^ ((r >> 2) & 15)) << 2));
}

#define DOT4(accv, av, bv) \
    accv = fmaf((av).x, (bv).x, fmaf((av).y, (bv).y, fmaf((av).z, (bv).z, fmaf((av).w, (bv).w, accv))))

// ---------------------------------------------------------------------------
// Kernel 1: QKV projection (y = x @ W.T + b), head split, RoPE for Q/K.
// 64x64 tile, 256 threads, 4x4 micro, K-chunk 64, swizzled b128 LDS reads.
// grid: (4096/64, 512/64, 3)   z: 0=Q 1=K 2=V
// ---------------------------------------------------------------------------
__global__ __launch_bounds__(256) void qkv_proj_rope(
    const float* __restrict__ x,
    const float* __restrict__ Wq, const float* __restrict__ bq,
    const float* __restrict__ Wk, const float* __restrict__ bk,
    const float* __restrict__ Wv, const float* __restrict__ bv,
    float* __restrict__ Qws, float* __restrict__ Kws, float* __restrict__ Vws)
{
    const int z = blockIdx.z;
    const float* __restrict__ W    = (z == 0) ? Wq : (z == 1) ? Wk : Wv;
    const float* __restrict__ bias = (z == 0) ? bq : (z == 1) ? bk : bv;
    float* __restrict__ outp       = (z == 0) ? Qws : (z == 1) ? Kws : Vws;

    __shared__ __align__(16) float Xs[64 * 64];
    __shared__ __align__(16) float Wt[64 * 64];

    const int t  = threadIdx.x;
    const int tx = t & 15, ty = t >> 4;
    const int mbase = blockIdx.x * 64;
    const int nbase = blockIdx.y * 64;

    const int sr  = t >> 2;         // 0..63 staging row
    const int sc0 = (t & 3) << 4;   // 0,16,32,48

    float acc[4][4] = {};

    for (int k0 = 0; k0 < DMODEL; k0 += 64) {
        __syncthreads();
        #pragma unroll
        for (int i = 0; i < 4; ++i) {
            const int c = sc0 + 4 * i;
            float4 xv = *(const float4*)(&x[(size_t)(mbase + sr) * DMODEL + k0 + c]);
            *tix4(Xs, sr, c >> 2) = xv;
            float4 wv = *(const float4*)(&W[(size_t)(nbase + sr) * DMODEL + k0 + c]);
            *tix4(Wt, sr, c >> 2) = wv;
        }
        __syncthreads();
        #pragma unroll
        for (int k4 = 0; k4 < 16; ++k4) {
            float4 a4[4], b4[4];
            #pragma unroll
            for (int i = 0; i < 4; ++i) a4[i] = *tix4c(Xs, (ty << 2) + i, k4);
            #pragma unroll
            for (int j = 0; j < 4; ++j) b4[j] = *tix4c(Wt, (tx << 2) + j, k4);
            #pragma unroll
            for (int i = 0; i < 4; ++i)
                #pragma unroll
                for (int j = 0; j < 4; ++j)
                    DOT4(acc[i][j], a4[i], b4[j]);
        }
    }

    const int jg0  = nbase + (tx << 2);
    const int head = jg0 >> 6;
    const int dim0 = jg0 & 63;
    const float b0 = bias[jg0 + 0], b1 = bias[jg0 + 1],
                b2 = bias[jg0 + 2], b3 = bias[jg0 + 3];

    #pragma unroll
    for (int i = 0; i < 4; ++i) {
        const int ig  = mbase + (ty << 2) + i;
        const int bb  = ig >> 11;     // batch
        const int pos = ig & 2047;
        float v0 = acc[i][0] + b0;
        float v1 = acc[i][1] + b1;
        float v2 = acc[i][2] + b2;
        float v3 = acc[i][3] + b3;
        if (z < 2) {
            const float fpos = (float)pos;
            const int d2a = dim0 >> 1;
            const int d2b = d2a + 1;
            const float invfa = exp2f(-ROPE_C * (float)d2a);
            const float invfb = exp2f(-ROPE_C * (float)d2b);
            float sa, ca, sb, cb;
            sincosf(fpos * invfa, &sa, &ca);
            sincosf(fpos * invfb, &sb, &cb);
            const float r0 = v0 * ca - v1 * sa;
            const float r1 = v1 * ca + v0 * sa;
            const float r2 = v2 * cb - v3 * sb;
            const float r3 = v3 * cb + v2 * sb;
            v0 = r0; v1 = r1; v2 = r2; v3 = r3;
        }
        *(float4*)(&outp[(((size_t)bb * NH + head) * L_SEQ + pos) * HD + dim0]) =
            make_float4(v0, v1, v2, v3);
    }
}

// ---------------------------------------------------------------------------
// Kernel 2: strictly-upper causal tiles: score = -1e9 exactly (|prev| < ulp/2)
// ---------------------------------------------------------------------------
__global__ __launch_bounds__(256) void fill_upper(float* __restrict__ out_score)
{
    const int q  = blockIdx.x;
    const int bh = blockIdx.y;
    const int kstart = ((q >> 6) + 1) << 6;
    float4* row = (float4*)(out_score + ((size_t)bh * L_SEQ + q) * L_SEQ);
    const float4 fv = make_float4(-1e9f, -1e9f, -1e9f, -1e9f);
    for (int c4 = (kstart >> 2) + threadIdx.x; c4 < (L_SEQ >> 2); c4 += 256)
        row[c4] = fv;
}

// ---------------------------------------------------------------------------
// Kernel 3: fused causal attention. 32-row q-tile, 64-col k-tile, 256 threads,
// 2x4 micro. LPT ordering (big q-tiles dispatch first). Swizzled b128 reads;
// V staged transposed (Vt[d][k]) so PV also reads float4 along k.
// grid: 1024 (g&15 = bh, qt = 63 - (g>>4))
// ---------------------------------------------------------------------------
__global__ __launch_bounds__(256) void attn_fused(
    const float* __restrict__ Qws, const float* __restrict__ Kws,
    const float* __restrict__ Vws, const float* __restrict__ prev,
    float* __restrict__ out_o, float* __restrict__ out_score)
{
    __shared__ __align__(16) float Qs[32 * 64];
    __shared__ __align__(16) float Ks[64 * 64];
    __shared__ __align__(16) float Vt[64 * 64];
    __shared__ __align__(16) float Ps[32 * 64];

    const int g   = blockIdx.x;
    const int bh  = g & 15;
    const int qt  = 63 - (g >> 4);     // descending workload => LPT schedule
    const int t   = threadIdx.x;
    const int tx  = t & 15, ty = t >> 4;   // ty 0..15 -> rows 2ty,2ty+1
    const int qbase = qt << 5;

    const size_t hoff = (size_t)bh * L_SEQ * HD;

    // stage Q tile (32 x 64)
    {
        const int r  = t >> 3;           // 0..31
        const int c0 = (t & 7) << 3;     // 0..56 step 8
        float4 q0 = *(const float4*)(&Qws[hoff + (size_t)(qbase + r) * HD + c0]);
        float4 q1 = *(const float4*)(&Qws[hoff + (size_t)(qbase + r) * HD + c0 + 4]);
        *tix4(Qs, r, (c0 >> 2) + 0) = q0;
        *tix4(Qs, r, (c0 >> 2) + 1) = q1;
    }

    float accO[2][4] = {};
    float m_i[2] = {-INFINITY, -INFINITY};
    float l_i[2] = {};

    const int nkt = (qt >> 1) + 1;
    const size_t prow0 = ((size_t)bh * L_SEQ + qbase) * L_SEQ;

    for (int kt = 0; kt < nkt; ++kt) {
        const int kbase = kt << 6;
        __syncthreads();   // prev PV done with Ks/Vt/Ps (also covers Q staging at kt=0)

        // stage K (64 x 64)
        {
            const int r  = t >> 2;          // 0..63
            const int c0 = (t & 3) << 4;    // 0,16,32,48
            #pragma unroll
            for (int i = 0; i < 4; ++i) {
                float4 kv = *(const float4*)(&Kws[hoff + (size_t)(kbase + r) * HD + c0 + 4 * i]);
                *tix4(Ks, r, (c0 >> 2) + i) = kv;
            }
        }
        // stage V transposed: Vt[d][kv]
        {
            const int kr0 = t >> 4;          // 0..15
            const int d0  = (t & 15) << 2;   // 0..60
            #pragma unroll
            for (int rr = 0; rr < 4; ++rr) {
                const int kv = kr0 + (rr << 4);
                float4 vv = *(const float4*)(&Vws[hoff + (size_t)(kbase + kv) * HD + d0]);
                Vt[tix(d0 + 0, kv)] = vv.x;
                Vt[tix(d0 + 1, kv)] = vv.y;
                Vt[tix(d0 + 2, kv)] = vv.z;
                Vt[tix(d0 + 3, kv)] = vv.w;
            }
        }
        __syncthreads();

        // S = Q K^T   (2x4 micro over hd=64)
        float s[2][4] = {};
        #pragma unroll
        for (int k4 = 0; k4 < 16; ++k4) {
            float4 a0 = *tix4c(Qs, 2 * ty + 0, k4);
            float4 a1 = *tix4c(Qs, 2 * ty + 1, k4);
            float4 b0 = *tix4c(Ks, (tx << 2) + 0, k4);
            float4 b1 = *tix4c(Ks, (tx << 2) + 1, k4);
            float4 b2 = *tix4c(Ks, (tx << 2) + 2, k4);
            float4 b3 = *tix4c(Ks, (tx << 2) + 3, k4);
            DOT4(s[0][0], a0, b0); DOT4(s[0][1], a0, b1);
            DOT4(s[0][2], a0, b2); DOT4(s[0][3], a0, b3);
            DOT4(s[1][0], a1, b0); DOT4(s[1][1], a1, b1);
            DOT4(s[1][2], a1, b2); DOT4(s[1][3], a1, b3);
        }

        // scale + causal mask + prev, write score; online softmax; write P
        #pragma unroll
        for (int i = 0; i < 2; ++i) {
            const int qrow = qbase + 2 * ty + i;
            const size_t off = prow0 + (size_t)(2 * ty + i) * L_SEQ + kbase + (tx << 2);
            const float4 pv = *(const float4*)(&prev[off]);
            const int kc = kbase + (tx << 2);
            const float v0 = (kc + 0 <= qrow) ? fmaf(s[i][0], 0.125f, pv.x) : -1e9f;
            const float v1 = (kc + 1 <= qrow) ? fmaf(s[i][1], 0.125f, pv.y) : -1e9f;
            const float v2 = (kc + 2 <= qrow) ? fmaf(s[i][2], 0.125f, pv.z) : -1e9f;
            const float v3 = (kc + 3 <= qrow) ? fmaf(s[i][3], 0.125f, pv.w) : -1e9f;
            *(float4*)(&out_score[off]) = make_float4(v0, v1, v2, v3);

            float mx = fmaxf(fmaxf(v0, v1), fmaxf(v2, v3));
            mx = fmaxf(mx, __shfl_xor(mx, 1));
            mx = fmaxf(mx, __shfl_xor(mx, 2));
            mx = fmaxf(mx, __shfl_xor(mx, 4));
            mx = fmaxf(mx, __shfl_xor(mx, 8));
            const float mnew = fmaxf(m_i[i], mx);
            const float sc = __expf(m_i[i] - mnew);  // kt=0: exp(-inf)=0
            const float p0 = __expf(v0 - mnew);
            const float p1 = __expf(v1 - mnew);
            const float p2 = __expf(v2 - mnew);
            const float p3 = __expf(v3 - mnew);
            float sum = p0 + p1 + p2 + p3;
            sum += __shfl_xor(sum, 1);
            sum += __shfl_xor(sum, 2);
            sum += __shfl_xor(sum, 4);
            sum += __shfl_xor(sum, 8);
            l_i[i] = l_i[i] * sc + sum;
            m_i[i] = mnew;
            accO[i][0] *= sc; accO[i][1] *= sc; accO[i][2] *= sc; accO[i][3] *= sc;
            *tix4(Ps, 2 * ty + i, tx) = make_float4(p0, p1, p2, p3);
        }
        __syncthreads();   // P visible (and everyone past Ks reads)

        // O += P V   (reads Ps rows, Vt rows; both float4 along k)
        #pragma unroll
        for (int k4 = 0; k4 < 16; ++k4) {
            float4 a0 = *tix4c(Ps, 2 * ty + 0, k4);
            float4 a1 = *tix4c(Ps, 2 * ty + 1, k4);
            float4 b0 = *tix4c(Vt, (tx << 2) + 0, k4);
            float4 b1 = *tix4c(Vt, (tx << 2) + 1, k4);
            float4 b2 = *tix4c(Vt, (tx << 2) + 2, k4);
            float4 b3 = *tix4c(Vt, (tx << 2) + 3, k4);
            DOT4(accO[0][0], a0, b0); DOT4(accO[0][1], a0, b1);
            DOT4(accO[0][2], a0, b2); DOT4(accO[0][3], a0, b3);
            DOT4(accO[1][0], a1, b0); DOT4(accO[1][1], a1, b1);
            DOT4(accO[1][2], a1, b2); DOT4(accO[1][3], a1, b3);
        }
    }

    // epilogue: O /= l, write (b, L, h*64+hd)
    const int bb = bh >> 3, hh = bh & 7;
    #pragma unroll
    for (int i = 0; i < 2; ++i) {
        const int qrow = qbase + 2 * ty + i;
        const float inv = 1.0f / l_i[i];
        *(float4*)(&out_o[((size_t)bb * L_SEQ + qrow) * DMODEL + hh * HD + (tx << 2)]) =
            make_float4(accO[i][0] * inv, accO[i][1] * inv,
                        accO[i][2] * inv, accO[i][3] * inv);
    }
}

// ---------------------------------------------------------------------------
extern "C" void kernel_launch(void* const* d_in, const int* in_sizes, int n_in,
                              void* d_out, int out_size, void* d_ws, size_t ws_size,
                              hipStream_t stream)
{
    const float* x    = (const float*)d_in[0];
    const float* prev = (const float*)d_in[1];
    const float* Wq   = (const float*)d_in[2];
    const float* bq   = (const float*)d_in[3];
    const float* Wk   = (const float*)d_in[4];
    const float* bk   = (const float*)d_in[5];
    const float* Wv   = (const float*)d_in[6];
    const float* bv   = (const float*)d_in[7];

    float* out_o     = (float*)d_out;
    float* out_score = out_o + (size_t)2 * L_SEQ * DMODEL;

    const size_t qkv_elems = (size_t)2 * NH * L_SEQ * HD;  // 2,097,152
    float* Qws = (float*)d_ws;
    float* Kws = Qws + qkv_elems;
    float* Vws = Kws + qkv_elems;

    qkv_proj_rope<<<dim3(4096 / 64, DMODEL / 64, 3), 256, 0, stream>>>(
        x, Wq, bq, Wk, bk, Wv, bv, Qws, Kws, Vws);

    fill_upper<<<dim3(L_SEQ, 16), 256, 0, stream>>>(out_score);

    attn_fused<<<dim3(1024), 256, 0, stream>>>(Qws, Kws, Vws, prev, out_o, out_score);
}

// Round 3
// 584.660 us; speedup vs baseline: 1.5129x; 1.4883x over previous
//
#include <hip/hip_runtime.h>
#include <hip/hip_bf16.h>
#include <math.h>

#define L_SEQ 2048
#define DM 512
#define NH 8
#define HD 64
// log2(10000)/32
#define ROPE_C 0.4152410118609203f

typedef __attribute__((ext_vector_type(8))) short bf16x8;
typedef __attribute__((ext_vector_type(8))) unsigned short u16x8;
typedef __attribute__((ext_vector_type(4))) float f32x4;

#define MFMA16(a, b, c) __builtin_amdgcn_mfma_f32_16x16x32_bf16((a), (b), (c), 0, 0, 0)

static __device__ __forceinline__ unsigned short f2bf(float f) {
    union { float f; unsigned int u; } c; c.f = f;
    unsigned int r = (c.u + 0x7fffu + ((c.u >> 16) & 1u)) >> 16;
    return (unsigned short)r;
}
static __device__ __forceinline__ float bf2f(unsigned short h) {
    union { unsigned int u; float f; } c; c.u = ((unsigned int)h) << 16;
    return c.f;
}

// ---------------------------------------------------------------------------
// Kernel 1: QKV projection via MFMA hi/lo split. y = x @ W.T + b, RoPE on Q/K,
// outputs split bf16 (hi+lo) for Q,K; single bf16 for V. Layout [bh][pos][64].
// 64x64 tile, 4 waves (wave w owns m-rows 16w..16w+15, all 64 n).
// grid: (64, 8, 3)  z: 0=Q 1=K 2=V
// LDS tiles 64x64 bf16, 128B rows, XOR-chunk swizzle (chunk ^= row&7).
// ---------------------------------------------------------------------------
__global__ __launch_bounds__(256) void qkv_proj_mfma(
    const float* __restrict__ x,
    const float* __restrict__ Wq, const float* __restrict__ bq,
    const float* __restrict__ Wk, const float* __restrict__ bk,
    const float* __restrict__ Wv, const float* __restrict__ bv,
    unsigned short* __restrict__ Qh, unsigned short* __restrict__ Ql,
    unsigned short* __restrict__ Kh, unsigned short* __restrict__ Kl,
    unsigned short* __restrict__ Vb)
{
    const int z = blockIdx.z;
    const float* __restrict__ W    = (z == 0) ? Wq : (z == 1) ? Wk : Wv;
    const float* __restrict__ bias = (z == 0) ? bq : (z == 1) ? bk : bv;

    __shared__ __align__(16) unsigned short Xh[64 * 64];
    __shared__ __align__(16) unsigned short Xl[64 * 64];
    __shared__ __align__(16) unsigned short Wh[64 * 64];
    __shared__ __align__(16) unsigned short Wl[64 * 64];

    const int t = threadIdx.x;
    const int w = t >> 6, l = t & 63;
    const int lr = l & 15, lg = l >> 4;
    const int mbase = blockIdx.x * 64;
    const int nbase = blockIdx.y * 64;

    const int sr = t & 63;            // staging row
    const int sc = (t >> 6) * 16;     // staging col (16 elems)

    f32x4 acc[4];
    #pragma unroll
    for (int nb = 0; nb < 4; ++nb) acc[nb] = (f32x4){0.f, 0.f, 0.f, 0.f};

    for (int k0 = 0; k0 < DM; k0 += 64) {
        __syncthreads();
        // stage x and W rows: 16 floats each -> hi/lo bf16, swizzled b128 writes
        {
            const int ch0 = (t >> 6) * 2, sw = sr & 7;
            const float* xs = &x[(size_t)(mbase + sr) * DM + k0 + sc];
            const float* ws = &W[(size_t)(nbase + sr) * DM + k0 + sc];
            float xv[16], wv[16];
            #pragma unroll
            for (int i = 0; i < 4; ++i) {
                float4 a = *(const float4*)(xs + 4 * i);
                xv[4 * i + 0] = a.x; xv[4 * i + 1] = a.y; xv[4 * i + 2] = a.z; xv[4 * i + 3] = a.w;
                float4 b = *(const float4*)(ws + 4 * i);
                wv[4 * i + 0] = b.x; wv[4 * i + 1] = b.y; wv[4 * i + 2] = b.z; wv[4 * i + 3] = b.w;
            }
            u16x8 xh0, xl0, xh1, xl1, wh0, wl0, wh1, wl1;
            #pragma unroll
            for (int i = 0; i < 8; ++i) {
                unsigned short h;
                h = f2bf(xv[i]);     xh0[i] = h; xl0[i] = f2bf(xv[i] - bf2f(h));
                h = f2bf(xv[i + 8]); xh1[i] = h; xl1[i] = f2bf(xv[i + 8] - bf2f(h));
                h = f2bf(wv[i]);     wh0[i] = h; wl0[i] = f2bf(wv[i] - bf2f(h));
                h = f2bf(wv[i + 8]); wh1[i] = h; wl1[i] = f2bf(wv[i + 8] - bf2f(h));
            }
            *(u16x8*)&Xh[sr * 64 + (((ch0    ) ^ sw) << 3)] = xh0;
            *(u16x8*)&Xh[sr * 64 + (((ch0 + 1) ^ sw) << 3)] = xh1;
            *(u16x8*)&Xl[sr * 64 + (((ch0    ) ^ sw) << 3)] = xl0;
            *(u16x8*)&Xl[sr * 64 + (((ch0 + 1) ^ sw) << 3)] = xl1;
            *(u16x8*)&Wh[sr * 64 + (((ch0    ) ^ sw) << 3)] = wh0;
            *(u16x8*)&Wh[sr * 64 + (((ch0 + 1) ^ sw) << 3)] = wh1;
            *(u16x8*)&Wl[sr * 64 + (((ch0    ) ^ sw) << 3)] = wl0;
            *(u16x8*)&Wl[sr * 64 + (((ch0 + 1) ^ sw) << 3)] = wl1;
        }
        __syncthreads();

        #pragma unroll
        for (int kc = 0; kc < 2; ++kc) {
            const int arow = w * 16 + lr;
            const int aofs = arow * 64 + (((4 * kc + lg) ^ (arow & 7)) << 3);
            bf16x8 ah = *(const bf16x8*)&Xh[aofs];
            bf16x8 al = *(const bf16x8*)&Xl[aofs];
            #pragma unroll
            for (int nb = 0; nb < 4; ++nb) {
                const int brow = nb * 16 + lr;
                const int bofs = brow * 64 + (((4 * kc + lg) ^ (brow & 7)) << 3);
                bf16x8 bh_ = *(const bf16x8*)&Wh[bofs];
                bf16x8 bl_ = *(const bf16x8*)&Wl[bofs];
                acc[nb] = MFMA16(ah, bl_, acc[nb]);
                acc[nb] = MFMA16(al, bh_, acc[nb]);
                acc[nb] = MFMA16(ah, bh_, acc[nb]);
            }
        }
    }

    // epilogue: bias + RoPE + split + store.  D-layout: col=lr (n), row=lg*4+r (m)
    #pragma unroll
    for (int nb = 0; nb < 4; ++nb) {
        const int n    = nbase + nb * 16 + lr;   // 0..511
        const int head = n >> 6;
        const int dim  = n & 63;
        const float bval = bias[n];
        const float invf = exp2f(-ROPE_C * (float)(dim >> 1));
        #pragma unroll
        for (int r = 0; r < 4; ++r) {
            const int mg    = mbase + w * 16 + lg * 4 + r;
            const int batch = mg >> 11;
            const int pos   = mg & 2047;
            float v = acc[nb][r] + bval;
            if (z < 2) {
                const float pv = __shfl_xor(v, 1);
                float s, c;
                sincosf((float)pos * invf, &s, &c);
                v = (dim & 1) ? fmaf(v, c, pv * s) : fmaf(v, c, -pv * s);
            }
            const size_t oidx = (((size_t)(batch * NH + head)) * L_SEQ + pos) * HD + dim;
            if (z == 2) {
                Vb[oidx] = f2bf(v);
            } else {
                const unsigned short h  = f2bf(v);
                const unsigned short lo = f2bf(v - bf2f(h));
                if (z == 0) { Qh[oidx] = h; Ql[oidx] = lo; }
                else        { Kh[oidx] = h; Kl[oidx] = lo; }
            }
        }
    }
}

// ---------------------------------------------------------------------------
// Kernel 2: fused causal attention, MFMA. Block = (bh, 64-row q-tile), 4 waves,
// wave w owns q-rows [16w,16w+16). K-tile 64. S via 3-term hi/lo split; PV via
// plain bf16 P,V. Online softmax per wave (rows wave-private). Also fills the
// strictly-upper -1e9 region for its rows. grid 512, balanced qt pairing.
// ---------------------------------------------------------------------------
__global__ __launch_bounds__(256) void attn_mfma(
    const unsigned short* __restrict__ Qh, const unsigned short* __restrict__ Ql,
    const unsigned short* __restrict__ Kh, const unsigned short* __restrict__ Kl,
    const unsigned short* __restrict__ Vb, const float* __restrict__ prev,
    float* __restrict__ out_o, float* __restrict__ out_score)
{
    __shared__ __align__(16) unsigned short Ksh[64 * 64];
    __shared__ __align__(16) unsigned short Ksl[64 * 64];
    __shared__ __align__(16) unsigned short Vt[64 * 64];   // transposed [d][k]
    __shared__ __align__(16) unsigned short Ps[4 * 16 * 64];

    const int g  = blockIdx.x;
    const int bh = g & 15;
    const int gq = g >> 4;                                // 0..31
    const int qt = (gq < 16) ? 31 - gq : gq - 16;         // paired sums = 31 (LPT-ish)
    const int t  = threadIdx.x;
    const int w  = t >> 6, l = t & 63;
    const int lr = l & 15, lg = l >> 4;
    const int qbase = qt << 6;

    const size_t hbase = (size_t)bh * L_SEQ * HD;

    // Q a-frags from global (per wave, rows 16w..16w+15)
    bf16x8 qhf[2], qlf[2];
    {
        const size_t qoff = hbase + (size_t)(qbase + w * 16 + lr) * HD + lg * 8;
        qhf[0] = *(const bf16x8*)&Qh[qoff];
        qhf[1] = *(const bf16x8*)&Qh[qoff + 32];
        qlf[0] = *(const bf16x8*)&Ql[qoff];
        qlf[1] = *(const bf16x8*)&Ql[qoff + 32];
    }

    f32x4 accO[4];
    #pragma unroll
    for (int db = 0; db < 4; ++db) accO[db] = (f32x4){0.f, 0.f, 0.f, 0.f};
    float m_i[4] = {-INFINITY, -INFINITY, -INFINITY, -INFINITY};
    float l_i[4] = {0.f, 0.f, 0.f, 0.f};

    for (int kt = 0; kt <= qt; ++kt) {
        const int kbase = kt << 6;
        __syncthreads();   // previous iteration done with Ksh/Ksl/Vt

        // prev loads issued early (latency hides under staging + QK^T)
        const size_t srow = ((size_t)bh * L_SEQ + (qbase + w * 16)) * L_SEQ + kbase;
        float pvv[4][4];
        #pragma unroll
        for (int kb = 0; kb < 4; ++kb)
            #pragma unroll
            for (int r = 0; r < 4; ++r)
                pvv[kb][r] = prev[srow + (size_t)(lg * 4 + r) * L_SEQ + kb * 16 + lr];

        // stage K hi/lo (row-major, swizzled) and V transposed
        {
            const int r = t & 63, c32 = t >> 6;
            const int ch0 = 2 * c32, sw = r & 7;
            const size_t koff = hbase + (size_t)(kbase + r) * HD + c32 * 16;
            u16x8 k0 = *(const u16x8*)&Kh[koff];
            u16x8 k1 = *(const u16x8*)&Kh[koff + 8];
            *(u16x8*)&Ksh[r * 64 + (((ch0    ) ^ sw) << 3)] = k0;
            *(u16x8*)&Ksh[r * 64 + (((ch0 + 1) ^ sw) << 3)] = k1;
            u16x8 k2 = *(const u16x8*)&Kl[koff];
            u16x8 k3 = *(const u16x8*)&Kl[koff + 8];
            *(u16x8*)&Ksl[r * 64 + (((ch0    ) ^ sw) << 3)] = k2;
            *(u16x8*)&Ksl[r * 64 + (((ch0 + 1) ^ sw) << 3)] = k3;

            const int vk = t & 63, vd0 = (t >> 6) * 16;
            const size_t voff = hbase + (size_t)(kbase + vk) * HD + vd0;
            u16x8 va = *(const u16x8*)&Vb[voff];
            u16x8 vb2 = *(const u16x8*)&Vb[voff + 8];
            #pragma unroll
            for (int e = 0; e < 8; ++e) {
                int d = vd0 + e;
                Vt[d * 64 + ((((vk >> 3) ^ (d & 7))) << 3) + (vk & 7)] = va[e];
                d = vd0 + 8 + e;
                Vt[d * 64 + ((((vk >> 3) ^ (d & 7))) << 3) + (vk & 7)] = vb2[e];
            }
        }
        __syncthreads();

        // S = Q K^T (3-term hi/lo split)
        f32x4 s[4];
        #pragma unroll
        for (int kb = 0; kb < 4; ++kb) s[kb] = (f32x4){0.f, 0.f, 0.f, 0.f};
        #pragma unroll
        for (int kc = 0; kc < 2; ++kc) {
            #pragma unroll
            for (int kb = 0; kb < 4; ++kb) {
                const int brow = kb * 16 + lr;
                const int bofs = brow * 64 + (((4 * kc + lg) ^ (brow & 7)) << 3);
                bf16x8 bh_ = *(const bf16x8*)&Ksh[bofs];
                bf16x8 bl_ = *(const bf16x8*)&Ksl[bofs];
                s[kb] = MFMA16(qhf[kc], bl_, s[kb]);
                s[kb] = MFMA16(qlf[kc], bh_, s[kb]);
                s[kb] = MFMA16(qhf[kc], bh_, s[kb]);
            }
        }

        // scale + mask + prev, score store
        float vout[4][4];
        #pragma unroll
        for (int kb = 0; kb < 4; ++kb) {
            #pragma unroll
            for (int r = 0; r < 4; ++r) {
                const int kg = kbase + kb * 16 + lr;
                const int qg = qbase + w * 16 + lg * 4 + r;
                const float v = (kg <= qg) ? fmaf(s[kb][r], 0.125f, pvv[kb][r]) : -1e9f;
                vout[kb][r] = v;
                out_score[srow + (size_t)(lg * 4 + r) * L_SEQ + kb * 16 + lr] = v;
            }
        }

        // online softmax (rows = lg*4+r, reduce across the 16 lanes of group lg)
        #pragma unroll
        for (int r = 0; r < 4; ++r) {
            float mx = fmaxf(fmaxf(vout[0][r], vout[1][r]), fmaxf(vout[2][r], vout[3][r]));
            mx = fmaxf(mx, __shfl_xor(mx, 1));
            mx = fmaxf(mx, __shfl_xor(mx, 2));
            mx = fmaxf(mx, __shfl_xor(mx, 4));
            mx = fmaxf(mx, __shfl_xor(mx, 8));
            const float mnew = fmaxf(m_i[r], mx);
            const float sc = __expf(m_i[r] - mnew);   // kt=0: exp(-inf)=0
            float p[4], psum = 0.f;
            #pragma unroll
            for (int kb = 0; kb < 4; ++kb) { p[kb] = __expf(vout[kb][r] - mnew); psum += p[kb]; }
            psum += __shfl_xor(psum, 1);
            psum += __shfl_xor(psum, 2);
            psum += __shfl_xor(psum, 4);
            psum += __shfl_xor(psum, 8);
            l_i[r] = l_i[r] * sc + psum;
            m_i[r] = mnew;
            #pragma unroll
            for (int db = 0; db < 4; ++db) accO[db][r] *= sc;
            const int qloc = lg * 4 + r, swp = qloc & 7;
            #pragma unroll
            for (int kb = 0; kb < 4; ++kb) {
                const int kcol = kb * 16 + lr;
                Ps[w * 1024 + qloc * 64 + ((((kcol >> 3) ^ swp)) << 3) + (kcol & 7)] = f2bf(p[kb]);
            }
        }

        // O += P V  (P wave-private in LDS; Vt shared)
        #pragma unroll
        for (int kc = 0; kc < 2; ++kc) {
            const int aofs = w * 1024 + lr * 64 + (((4 * kc + lg) ^ (lr & 7)) << 3);
            bf16x8 pa = *(const bf16x8*)&Ps[aofs];
            #pragma unroll
            for (int db = 0; db < 4; ++db) {
                const int vrow = db * 16 + lr;
                const int bofs = vrow * 64 + (((4 * kc + lg) ^ (vrow & 7)) << 3);
                bf16x8 vf = *(const bf16x8*)&Vt[bofs];
                accO[db] = MFMA16(pa, vf, accO[db]);
            }
        }
    }

    // epilogue: O /= l, write o
    const int bb = bh >> 3, hh = bh & 7;
    #pragma unroll
    for (int r = 0; r < 4; ++r) {
        const int qg = qbase + w * 16 + lg * 4 + r;
        const float inv = 1.0f / l_i[r];
        #pragma unroll
        for (int db = 0; db < 4; ++db)
            out_o[((size_t)bb * L_SEQ + qg) * DM + hh * HD + db * 16 + lr] = accO[db][r] * inv;
    }

    // fill strictly-upper remainder for this block's 64 rows: exactly -1e9
    // (|prev| < half-ulp(1e9) => -1e9 + prev rounds to -1e9 in fp32)
    const int endk = (qt + 1) << 6;
    if (endk < L_SEQ) {
        const float4 fv = make_float4(-1e9f, -1e9f, -1e9f, -1e9f);
        const int row = qbase + (t >> 2);
        const size_t rb = ((size_t)bh * L_SEQ + row) * L_SEQ;
        for (int c = endk + (t & 3) * 4; c < L_SEQ; c += 16)
            *(float4*)&out_score[rb + c] = fv;
    }
}

// ---------------------------------------------------------------------------
extern "C" void kernel_launch(void* const* d_in, const int* in_sizes, int n_in,
                              void* d_out, int out_size, void* d_ws, size_t ws_size,
                              hipStream_t stream)
{
    const float* x    = (const float*)d_in[0];
    const float* prev = (const float*)d_in[1];
    const float* Wq   = (const float*)d_in[2];
    const float* bq   = (const float*)d_in[3];
    const float* Wk   = (const float*)d_in[4];
    const float* bk   = (const float*)d_in[5];
    const float* Wv   = (const float*)d_in[6];
    const float* bv   = (const float*)d_in[7];

    float* out_o     = (float*)d_out;
    float* out_score = out_o + (size_t)2 * L_SEQ * DM;

    const size_t qkv_elems = (size_t)2 * NH * L_SEQ * HD;  // 2,097,152
    unsigned short* Qh = (unsigned short*)d_ws;
    unsigned short* Ql = Qh + qkv_elems;
    unsigned short* Kh = Ql + qkv_elems;
    unsigned short* Kl = Kh + qkv_elems;
    unsigned short* Vb = Kl + qkv_elems;

    qkv_proj_mfma<<<dim3(64, 8, 3), 256, 0, stream>>>(
        x, Wq, bq, Wk, bk, Wv, bv, Qh, Ql, Kh, Kl, Vb);

    attn_mfma<<<dim3(512), 256, 0, stream>>>(
        Qh, Ql, Kh, Kl, Vb, prev, out_o, out_score);
}